// Round 7
// baseline (337.954 us; speedup 1.0000x reference)
//
#include <hip/hip_runtime.h>
#include <hip/hip_bf16.h>
#include <stdint.h>

typedef __bf16 bf16;
typedef __attribute__((ext_vector_type(8))) __bf16 bf16x8;
typedef __attribute__((ext_vector_type(4))) __bf16 bf16x4;
typedef __attribute__((ext_vector_type(4))) float  f32x4;

// ---- async global->LDS, 16B per lane, dest = wave-uniform base (+ lane*16 in HW) ----
static __device__ __forceinline__ void gll16(const void* g, void* lds_base) {
  __builtin_amdgcn_global_load_lds((__attribute__((address_space(1))) void*)g,
                                   (__attribute__((address_space(3))) void*)lds_base,
                                   16, 0, 0);
}

#define BARR  __builtin_amdgcn_s_barrier()
#define VMW(N) asm volatile("s_waitcnt vmcnt(" #N ")" ::: "memory")
#define LGKM0 asm volatile("s_waitcnt lgkmcnt(0)" ::: "memory")
#define SB0   __builtin_amdgcn_sched_barrier(0)

// ============================================================================
// 256x256 BT-GEMM (D = A*B^T, K-contiguous, ld=1024), BK=64, 8 waves (2Mx4N),
// 2 phases per K-tile, double-buffered LDS, (row&7)<<4 XOR-swizzle (0 bank
// conflicts, verified R4/R6), counted vmcnt.
//  bf16-A path (VARIANT 2,3): EXACT R6 core (42.3 us, 810 TF measured).
//  fp32-A path (VARIANT 0,1): A read fp32-direct (no pre-pass). Per tile:
//    P1: issue 4x dwordx4 (A-half0(u+1) -> rQ bank, 16 VGPR)
//    P2: vmcnt(0); cvt+swizzled ds_write half0 -> slot cur^1; issue half1
//        loads into rQ; stage B(u+2) gll; after cluster vmcnt(4); write half1.
//    Register budget kept flat vs R6 by k-split clusters: af[4] (16 VGPR, one
//    kh at a time; mid-cluster ds_read + lgkm0 + sched_barrier per rule #18)
//    instead of af[4][2] (32). acc 128 (AGPR) + bfr 32 + af 16 + rQ 16.
// VARIANT: 0 proj -> Cb row-major [M][1024] bf16
//          1 proj -> Cb = per-batch transposed v^T [b][h][t] bf16
//          2 qk   -> Cb = S bf16 (scale; causal writes 0, pad -inf;
//                    jt==it+1 zero-fill, jt>it+1 skipped entirely)
//          3 pv   -> Cf = O f32, K-loop causally truncated
// ============================================================================
#define MFMA_CLUSTER(MQ)                                                       \
  __builtin_amdgcn_s_barrier();                                                \
  asm volatile("s_waitcnt lgkmcnt(0)" ::: "memory");                           \
  __builtin_amdgcn_sched_barrier(0);                                           \
  __builtin_amdgcn_s_setprio(1);                                               \
  _Pragma("unroll") for (int i_ = 0; i_ < 4; ++i_)                             \
  _Pragma("unroll") for (int n_ = 0; n_ < 4; ++n_)                             \
  _Pragma("unroll") for (int kh_ = 0; kh_ < 2; ++kh_)                          \
    acc[(MQ) * 4 + i_][n_] = __builtin_amdgcn_mfma_f32_16x16x32_bf16(          \
        af2[i_][kh_], bfr[n_][kh_], acc[(MQ) * 4 + i_][n_], 0, 0, 0);          \
  __builtin_amdgcn_s_setprio(0);

template <int VARIANT>
__global__ __launch_bounds__(512, 2) void gemm8(const void* __restrict__ Araw,
                                                const bf16* __restrict__ B,
                                                bf16* __restrict__ Cb,
                                                float* __restrict__ Cf,
                                                const int* __restrict__ pad) {
  constexpr bool FP32A = (VARIANT <= 1);
  extern __shared__ char smem[];         // A: 2 x 32KB | B: 2 x 32KB
  char* ldsA = smem;
  char* ldsB = smem + 65536;

  const int tid = threadIdx.x;
  const int lane = tid & 63, wave = tid >> 6;
  const int lo = lane & 15, hi = lane >> 4;
  const int wmi = wave >> 2, wni = wave & 3;
  const int swz = (lo & 7) << 4;         // read-side XOR: (row&7)<<4, row&7 == lo&7

  // XCD-chunked bijective swizzle (gridDim.x % 8 == 0 for all launches)
  const int nwg = gridDim.x;
  const int id = (blockIdx.x % 8) * (nwg >> 3) + blockIdx.x / 8;

  int row0, col0, nt, b = 0;
  if (VARIANT <= 1) {
    row0 = (id >> 2) * 256; col0 = (id & 3) * 256; nt = 16;
  } else {
    b = id >> 4;
    const int r = id & 15, it = r >> 2, jt = r & 3;
    row0 = it * 256; col0 = jt * 256;
    nt = (VARIANT == 3) ? min(16, 4 * it + 6) : 16;
    if (VARIANT == 2 && jt > it + 1) return;     // never read downstream
    if (VARIANT == 2 && jt == it + 1) {          // zero-fill (corner fixed later)
      bf16* Sb = Cb + ((size_t)b << 20);
      bf16x8 z = {};
#pragma unroll
      for (int q = 0; q < 16; ++q) {
        const int off = (q * 512 + tid) * 8;
        *(bf16x8*)(Sb + (size_t)(row0 + (off >> 8)) * 1024 + col0 + (off & 255)) = z;
      }
      return;
    }
  }
  const int ntm1 = nt - 1;
  const float* Afp = FP32A ? (const float*)Araw + (size_t)row0 * 1024 : nullptr;
  const bf16*  Ab  = FP32A ? nullptr
                           : (const bf16*)Araw + ((size_t)b << 20) + (size_t)row0 * 1024;
  const bf16*  Bp  = B + (FP32A ? (size_t)0 : ((size_t)b << 20)) + (size_t)col0 * 1024;

  // stage one full 256x64 bf16 operand K-tile (32KB): 4 gll/wave
  auto stgB = [&](int tidx, int slot) {
    const int tc = tidx > ntm1 ? ntm1 : tidx;
#pragma unroll
    for (int r = 0; r < 4; ++r) {
      const int x  = (wave * 4 + r) * 1024 + lane * 16;
      const int xs = x ^ (((x >> 7) & 7) << 4);
      gll16((const char*)Bp + (size_t)(xs >> 7) * 2048 + (size_t)tc * 128 + (xs & 127),
            ldsB + slot * 32768 + (wave * 4 + r) * 1024);
    }
  };
  auto stgA = [&](int tidx, int slot) {     // bf16-A path only
    const int tc = tidx > ntm1 ? ntm1 : tidx;
#pragma unroll
    for (int r = 0; r < 4; ++r) {
      const int x  = (wave * 4 + r) * 1024 + lane * 16;
      const int xs = x ^ (((x >> 7) & 7) << 4);
      gll16((const char*)Ab + (size_t)(xs >> 7) * 2048 + (size_t)tc * 128 + (xs & 127),
            ldsA + slot * 32768 + (wave * 4 + r) * 1024);
    }
  };

  f32x4 acc[8][4] = {};
  bf16x8 bfr[4][2];

  auto rdBall = [&](int slot) {
#pragma unroll
    for (int n = 0; n < 4; ++n)
#pragma unroll
      for (int kh = 0; kh < 2; ++kh) {
        const int row = wni * 64 + n * 16 + lo;
        bfr[n][kh] = *(const bf16x8*)(ldsB + slot * 32768 +
                                      ((row * 128 + kh * 64 + hi * 16) ^ swz));
      }
  };

  if constexpr (FP32A) {
    // ======================= fp32-A projection path =======================
    bf16x8 af[4];
    f32x4 rQ[4];
    // A-half load: half h rows [h*128, h*128+128); thread -> row h*128+(tid>>2),
    // fp32 cols (tid&3)*16 .. +16 of the 64-wide K-tile.  4x dwordx4.
    auto glbAh = [&](int h, int t) {
      const int tc = t > ntm1 ? ntm1 : t;
      const float* p = Afp + (size_t)(h * 128 + (tid >> 2)) * 1024 +
                       (size_t)tc * 64 + (tid & 3) * 16;
      rQ[0] = *(const f32x4*)(p);
      rQ[1] = *(const f32x4*)(p + 4);
      rQ[2] = *(const f32x4*)(p + 8);
      rQ[3] = *(const f32x4*)(p + 12);
    };
    auto wrAh = [&](int h, int slot) {      // cvt 16 f32 -> 2x ds_write_b128
      const int row = h * 128 + (tid >> 2);
      const int base = row * 128 + (tid & 3) * 32;
      const int key = (row & 7) << 4;
      char* d = ldsA + slot * 32768;
      bf16x8 o0 = { (bf16)rQ[0][0], (bf16)rQ[0][1], (bf16)rQ[0][2], (bf16)rQ[0][3],
                    (bf16)rQ[1][0], (bf16)rQ[1][1], (bf16)rQ[1][2], (bf16)rQ[1][3] };
      bf16x8 o1 = { (bf16)rQ[2][0], (bf16)rQ[2][1], (bf16)rQ[2][2], (bf16)rQ[2][3],
                    (bf16)rQ[3][0], (bf16)rQ[3][1], (bf16)rQ[3][2], (bf16)rQ[3][3] };
      *(bf16x8*)(d + (base ^ key)) = o0;
      *(bf16x8*)(d + ((base + 16) ^ key)) = o1;
    };
    auto rdAk = [&](int mh, int kh, int slot) {
#pragma unroll
      for (int i = 0; i < 4; ++i) {
        const int row = wmi * 128 + mh * 64 + i * 16 + lo;
        af[i] = *(const bf16x8*)(ldsA + slot * 32768 +
                                 ((row * 128 + kh * 64 + hi * 16) ^ swz));
      }
    };
    auto mmaK = [&](int mh, int kh) {
#pragma unroll
      for (int i = 0; i < 4; ++i)
#pragma unroll
        for (int n = 0; n < 4; ++n)
          acc[mh * 4 + i][n] = __builtin_amdgcn_mfma_f32_16x16x32_bf16(
              af[i], bfr[n][kh], acc[mh * 4 + i][n], 0, 0, 0);
    };

    // prologue: A(0)->slot0 via reg-cvt; B(0)->slot0, B(1)->slot1 via gll
    glbAh(0, 0); VMW(0); wrAh(0, 0);
    glbAh(1, 0); VMW(0); wrAh(1, 0);
    stgB(0, 0); stgB(1, 1);
    VMW(4);                                 // retire B(0); B(1) in flight
    LGKM0; BARR;

#pragma unroll 2
    for (int u = 0; u < nt; ++u) {
      const int cur = u & 1;
      // ---- P1: A(mh0) reads + B reads; issue A-half0(u+1) fp32 loads ----
      rdAk(0, 0, cur);
      rdBall(cur);
      glbAh(0, u + 1);
      BARR; LGKM0; SB0;
      __builtin_amdgcn_s_setprio(1);
      mmaK(0, 0);
      rdAk(0, 1, cur); LGKM0; SB0;
      mmaK(0, 1);
      __builtin_amdgcn_s_setprio(0);
      BARR;
      // ---- P2: A(mh1) reads; land+write A-half0(u+1); issue half1; B(u+2) ----
      rdAk(1, 0, cur);
      VMW(0);                               // glbA_h0(u+1) + stgB(u+1) complete
      wrAh(0, cur ^ 1);
      glbAh(1, u + 1);
      stgB(u + 2, cur);
      BARR; LGKM0; SB0;
      __builtin_amdgcn_s_setprio(1);
      mmaK(1, 0);
      rdAk(1, 1, cur); LGKM0; SB0;
      mmaK(1, 1);
      __builtin_amdgcn_s_setprio(0);
      VMW(4);                               // retire glbA_h1(u+1); keep B(u+2)
      wrAh(1, cur ^ 1);
      LGKM0;                                // writes visible before epoch ends
      BARR;
    }
  } else {
    // ======================= bf16-A path (EXACT R6 core) ==================
    bf16x8 af2[4][2];
    // prologue: establish steady-state invariant (tile0 landed, B(1) in flight)
    stgB(0, 0);
    stgA(0, 0);
    stgB(1, 1);
    VMW(4);                                 // retire B(0),A(0); keep B(1)
    BARR;

#pragma unroll 2
    for (int u = 0; u < nt; ++u) {
      const int cur = u & 1;
      // ---- Phase 1: A rows [wmi*128, +64) + ALL of wave's B quarter ----
#pragma unroll
      for (int i_ = 0; i_ < 4; ++i_)
#pragma unroll
        for (int kh_ = 0; kh_ < 2; ++kh_) {
          const int row_ = wmi * 128 + i_ * 16 + lo;
          af2[i_][kh_] = *(const bf16x8*)(ldsA + cur * 32768 +
                                          ((row_ * 128 + kh_ * 64 + hi * 16) ^ swz));
        }
      rdBall(cur);
      stgA(u + 1, cur ^ 1);
      MFMA_CLUSTER(0)
      BARR;
      // ---- Phase 2: A rows [wmi*128+64, +64), reuse bfr from registers ----
#pragma unroll
      for (int i_ = 0; i_ < 4; ++i_)
#pragma unroll
        for (int kh_ = 0; kh_ < 2; ++kh_) {
          const int row_ = wmi * 128 + 64 + i_ * 16 + lo;
          af2[i_][kh_] = *(const bf16x8*)(ldsA + cur * 32768 +
                                          ((row_ * 128 + kh_ * 64 + hi * 16) ^ swz));
        }
      stgB(u + 2, cur);
      MFMA_CLUSTER(1)
      VMW(4);                               // retire A(u+1),B(u+1); keep B(u+2)
      BARR;
    }
  }

  // ---- epilogue ----
  if (VARIANT == 0) {
#pragma unroll
    for (int m = 0; m < 8; ++m)
#pragma unroll
      for (int n = 0; n < 4; ++n) {
        const int c = col0 + wni * 64 + n * 16 + lo;
        const int rbase = row0 + wmi * 128 + m * 16 + hi * 4;
#pragma unroll
        for (int j = 0; j < 4; ++j)
          Cb[(size_t)(rbase + j) * 1024 + c] = (bf16)acc[m][n][j];
      }
  } else if (VARIANT == 1) {
#pragma unroll
    for (int m = 0; m < 8; ++m)
#pragma unroll
      for (int n = 0; n < 4; ++n) {
        const int r = row0 + wmi * 128 + m * 16 + hi * 4;
        const int c = col0 + wni * 64 + n * 16 + lo;
        const int bb = r >> 10, tt = r & 1023;
        bf16x4 h = { (bf16)acc[m][n][0], (bf16)acc[m][n][1],
                     (bf16)acc[m][n][2], (bf16)acc[m][n][3] };
        *(bf16x4*)(Cb + ((size_t)bb << 20) + ((size_t)c << 10) + tt) = h;
      }
  } else if (VARIANT == 2) {
    const float NINF = -__builtin_inff();
#pragma unroll
    for (int n = 0; n < 4; ++n) {
      const int s = col0 + wni * 64 + n * 16 + lo;
      const int pd = pad[(b << 10) + s];
#pragma unroll
      for (int m = 0; m < 8; ++m) {
        const int tbase = row0 + wmi * 128 + m * 16 + hi * 4;
#pragma unroll
        for (int j = 0; j < 4; ++j) {
          float v = acc[m][n][j] * 0.03125f;          // 1/sqrt(1024)
          if (s > tbase + j + 1) v = 0.f;             // causal: raw 0, softmax skips
          else if (pd != 0) v = NINF;                 // pad: true -inf inside width
          Cb[((size_t)b << 20) + (size_t)(tbase + j) * 1024 + s] = (bf16)v;
        }
      }
    }
  } else {
#pragma unroll
    for (int m = 0; m < 8; ++m)
#pragma unroll
      for (int n = 0; n < 4; ++n) {
        const int h2 = col0 + wni * 64 + n * 16 + lo;
        const int tbase = row0 + wmi * 128 + m * 16 + hi * 4;
#pragma unroll
        for (int j = 0; j < 4; ++j)
          Cf[((size_t)b << 20) + (size_t)(tbase + j) * 1024 + h2] = acc[m][n][j];
      }
  }
  asm volatile("s_waitcnt vmcnt(0)" ::: "memory");   // drain clamped stages before exit
}

// ---- all three weight matrices in one launch (512 blocks each) ----
__global__ __launch_bounds__(256) void cvtW_kernel(const float* __restrict__ s0,
                                                   const float* __restrict__ s1,
                                                   const float* __restrict__ s2,
                                                   bf16* __restrict__ d0,
                                                   bf16* __restrict__ d1,
                                                   bf16* __restrict__ d2) {
  const int seg = blockIdx.x >> 9, blk = blockIdx.x & 511;
  const float* src = seg == 0 ? s0 : (seg == 1 ? s1 : s2);
  bf16* dst = seg == 0 ? d0 : (seg == 1 ? d1 : d2);
  const int i = (blk * 256 + threadIdx.x) * 8;
  const f32x4 a = *(const f32x4*)(src + i);
  const f32x4 b = *(const f32x4*)(src + i + 4);
  bf16x8 o = { (bf16)a[0], (bf16)a[1], (bf16)a[2], (bf16)a[3],
               (bf16)b[0], (bf16)b[1], (bf16)b[2], (bf16)b[3] };
  *(bf16x8*)(dst + i) = o;
}

// ---- the single valid element on each jt==it+1 tile: S[t=it*256+255][s=(it+1)*256] ----
__global__ __launch_bounds__(64) void corner_kernel(const bf16* __restrict__ Q,
                                                    const bf16* __restrict__ K,
                                                    const int* __restrict__ pad,
                                                    bf16* __restrict__ S) {
  const int b = blockIdx.x / 3, it = blockIdx.x % 3;
  const int t = it * 256 + 255, s = (it + 1) * 256;
  const int lane = threadIdx.x;
  const bf16* q = Q + ((size_t)b << 20) + (size_t)t * 1024 + lane * 16;
  const bf16* k = K + ((size_t)b << 20) + (size_t)s * 1024 + lane * 16;
  bf16x8 q0 = *(const bf16x8*)q, q1 = *(const bf16x8*)(q + 8);
  bf16x8 k0 = *(const bf16x8*)k, k1 = *(const bf16x8*)(k + 8);
  float d = 0.f;
#pragma unroll
  for (int j = 0; j < 8; ++j) d += (float)q0[j] * (float)k0[j] + (float)q1[j] * (float)k1[j];
#pragma unroll
  for (int o = 32; o; o >>= 1) d += __shfl_xor(d, o, 64);
  if (lane == 0) {
    float v = d * 0.03125f;
    if (pad[(b << 10) + s] != 0) v = -__builtin_inff();
    S[((size_t)b << 20) + (size_t)t * 1024 + s] = (bf16)v;
  }
}

// ---- row softmax in place over valid prefix w = t+2 (causal tail stays 0) ----
__global__ __launch_bounds__(256) void softmax_kernel(bf16* __restrict__ S) {
  const int row  = blockIdx.x * 4 + (threadIdx.x >> 6);
  const int lane = threadIdx.x & 63;
  const int t = row & 1023;
  const int w = min(1024, t + 2);
  const bool act = lane * 16 < w;
  bf16* r = S + (size_t)row * 1024 + lane * 16;
  bf16x8 v0 = {}, v1 = {};
  float f[16];
#pragma unroll
  for (int j = 0; j < 16; ++j) f[j] = -1e30f;
  if (act) {
    v0 = *(const bf16x8*)r;
    v1 = *(const bf16x8*)(r + 8);
#pragma unroll
    for (int j = 0; j < 16; ++j)
      if (lane * 16 + j < w) f[j] = (float)(j < 8 ? v0[j] : v1[j - 8]);
  }
  float m = f[0];
#pragma unroll
  for (int j = 1; j < 16; ++j) m = fmaxf(m, f[j]);
#pragma unroll
  for (int o = 32; o; o >>= 1) m = fmaxf(m, __shfl_xor(m, o, 64));
  float sum = 0.f;
  float e[16];
#pragma unroll
  for (int j = 0; j < 16; ++j) { e[j] = __expf(f[j] - m); sum += e[j]; }
#pragma unroll
  for (int o = 32; o; o >>= 1) sum += __shfl_xor(sum, o, 64);
  const float inv = 1.0f / sum;
  if (act) {
#pragma unroll
    for (int j = 0; j < 8; ++j) {
      v0[j] = (bf16)(lane * 16 + j < w ? e[j] * inv : 0.f);
      v1[j] = (bf16)(lane * 16 + 8 + j < w ? e[8 + j] * inv : 0.f);
    }
    *(bf16x8*)r = v0;
    *(bf16x8*)(r + 8) = v1;
  }
}

extern "C" void kernel_launch(void* const* d_in, const int* in_sizes, int n_in,
                              void* d_out, int out_size, void* d_ws, size_t ws_size,
                              hipStream_t stream) {
  const float* key   = (const float*)d_in[0];
  const float* query = (const float*)d_in[1];
  const float* value = (const float*)d_in[2];
  const int*   pad   = (const int*)d_in[3];
  const float* Wk    = (const float*)d_in[4];
  const float* Wq    = (const float*)d_in[5];
  const float* Wv    = (const float*)d_in[6];
  float* out = (float*)d_out;

  // ws (bf16 elems): Wk,Wq,Wv (1M each) | q 16M | k 16M | vT 16M | S 16M
  bf16* Wkb = (bf16*)d_ws;
  bf16* Wqb = Wkb + (1 << 20);
  bf16* Wvb = Wqb + (1 << 20);
  bf16* qb  = Wvb + (1 << 20);
  bf16* kb  = qb  + (16 << 20);
  bf16* vT  = kb  + (16 << 20);
  bf16* S   = vT  + (16 << 20);

  hipFuncSetAttribute(reinterpret_cast<const void*>(&gemm8<0>),
                      hipFuncAttributeMaxDynamicSharedMemorySize, 131072);
  hipFuncSetAttribute(reinterpret_cast<const void*>(&gemm8<1>),
                      hipFuncAttributeMaxDynamicSharedMemorySize, 131072);
  hipFuncSetAttribute(reinterpret_cast<const void*>(&gemm8<2>),
                      hipFuncAttributeMaxDynamicSharedMemorySize, 131072);
  hipFuncSetAttribute(reinterpret_cast<const void*>(&gemm8<3>),
                      hipFuncAttributeMaxDynamicSharedMemorySize, 131072);

  cvtW_kernel<<<1536, 256, 0, stream>>>(Wk, Wq, Wv, Wkb, Wqb, Wvb);

  gemm8<0><<<256, 512, 131072, stream>>>((const void*)query, Wqb, qb, nullptr, nullptr);
  gemm8<0><<<256, 512, 131072, stream>>>((const void*)key,   Wkb, kb, nullptr, nullptr);
  gemm8<1><<<256, 512, 131072, stream>>>((const void*)value, Wvb, vT, nullptr, nullptr);

  gemm8<2><<<256, 512, 131072, stream>>>((const void*)qb, kb, S, nullptr, pad);
  corner_kernel<<<48, 64, 0, stream>>>(qb, kb, pad, S);
  softmax_kernel<<<4096, 256, 0, stream>>>(S);
  gemm8<3><<<256, 512, 131072, stream>>>((const void*)S, vT, nullptr, out, nullptr);
}

// Round 8
// 249.867 us; speedup vs baseline: 1.3525x; 1.3525x over previous
//
#include <hip/hip_runtime.h>
#include <hip/hip_bf16.h>
#include <stdint.h>

typedef __bf16 bf16;
typedef __attribute__((ext_vector_type(8))) __bf16 bf16x8;
typedef __attribute__((ext_vector_type(4))) __bf16 bf16x4;
typedef __attribute__((ext_vector_type(4))) float  f32x4;

// ---- async global->LDS, 16B per lane, dest = wave-uniform base (+ lane*16 in HW) ----
static __device__ __forceinline__ void gll16(const void* g, void* lds_base) {
  __builtin_amdgcn_global_load_lds((__attribute__((address_space(1))) void*)g,
                                   (__attribute__((address_space(3))) void*)lds_base,
                                   16, 0, 0);
}

#define BARR  __builtin_amdgcn_s_barrier()
#define VMW(N) asm volatile("s_waitcnt vmcnt(" #N ")" ::: "memory")
#define LGKM0 asm volatile("s_waitcnt lgkmcnt(0)" ::: "memory")
#define SB0   __builtin_amdgcn_sched_barrier(0)

// ============================================================================
// 256x256 BT-GEMM (D = A*B^T, both K-contiguous, ld=1024), BK=32, 8 waves
// (2Mx4N), 2 phases per K-tile (B quarter in regs across both phases),
// double-buffered 64 KiB LDS -> 2 blocks/CU (cross-block overlap hides the
// barrier/vmcnt drains that capped R6's 128KiB/1-block config at 810 TF).
// (row&3)<<4 XOR-swizzle (involution-safe at 64B row stride; linear gll dest
// + inverse-swizzled global src + swizzled ds_read). Counted vmcnt(2)/K-tile.
// Schedule = R6-proven core, rescaled: prologue {B(0),A(0),B(1); vmcnt(2)};
// P1 stages A(u+1)->slot^1; P2 stages B(u+2)->slot; tile-end vmcnt(2)+barrier.
// VARIANT: 0 = merged projections: blocks [0,256) query->qb (row-major),
//              [256,512) key->kb (row-major), [512,768) value->vT (transposed
//              per-batch [b][h][t] epilogue).
//          2 = qk -> S bf16 (scale; causal writes 0, pad -inf; jt==it+1
//              zero-fill, jt>it+1 skipped entirely)
//          3 = pv -> out f32, K-loop causally truncated
// ============================================================================
template <int VARIANT>
__global__ __launch_bounds__(512, 2) void gemm8(const bf16* __restrict__ a0,
                                                const bf16* __restrict__ a1,
                                                const bf16* __restrict__ a2,
                                                const bf16* __restrict__ b0,
                                                const bf16* __restrict__ b1,
                                                const bf16* __restrict__ b2,
                                                bf16* __restrict__ c0,
                                                bf16* __restrict__ c1,
                                                bf16* __restrict__ c2,
                                                float* __restrict__ Cf,
                                                const int* __restrict__ pad) {
  extern __shared__ char smem[];         // A: 2 x 16KB | B: 2 x 16KB
  char* ldsA = smem;
  char* ldsB = smem + 32768;

  const int tid = threadIdx.x;
  const int lane = tid & 63, wave = tid >> 6;
  const int lo = lane & 15, hi = lane >> 4;
  const int wmi = wave >> 2, wni = wave & 3;
  const int swz = (lo & 3) << 4;         // read-side XOR key = (row&3)<<4

  // XCD-chunked bijective swizzle (gridDim.x % 8 == 0 for all launches)
  const int nwg = gridDim.x;
  const int id = (blockIdx.x % 8) * (nwg >> 3) + blockIdx.x / 8;

  int row0, col0, nt, batch = 0, trans = 0;
  const bf16 *Ap, *Bp;
  bf16* Cb;
  if (VARIANT == 0) {
    const int seg = id >> 8, idl = id & 255;
    row0 = (idl >> 2) * 256; col0 = (idl & 3) * 256; nt = 32;
    trans = (seg == 2);
    const bf16* As = seg == 0 ? a0 : (seg == 1 ? a1 : a2);
    const bf16* Bs = seg == 0 ? b0 : (seg == 1 ? b1 : b2);
    Cb = seg == 0 ? c0 : (seg == 1 ? c1 : c2);
    Ap = As + (size_t)row0 * 1024;
    Bp = Bs + (size_t)col0 * 1024;
  } else {
    batch = id >> 4;
    const int r = id & 15, it = r >> 2, jt = r & 3;
    row0 = it * 256; col0 = jt * 256;
    nt = (VARIANT == 3) ? min(32, 8 * it + 10) : 32;   // pv causal truncation (even)
    if (VARIANT == 2 && jt > it + 1) return;           // never read downstream
    if (VARIANT == 2 && jt == it + 1) {                // zero-fill (corner fixed later)
      bf16* Sb = c0 + ((size_t)batch << 20);
      bf16x8 z = {};
#pragma unroll
      for (int q = 0; q < 16; ++q) {
        const int off = (q * 512 + tid) * 8;
        *(bf16x8*)(Sb + (size_t)(row0 + (off >> 8)) * 1024 + col0 + (off & 255)) = z;
      }
      return;
    }
    Ap = a0 + ((size_t)batch << 20) + (size_t)row0 * 1024;
    Bp = b0 + ((size_t)batch << 20) + (size_t)col0 * 1024;
    Cb = c0;
  }
  const int ntm1 = nt - 1;

  // stage one full 256x32 operand K-tile (16KB): 2 gll/wave, linear LDS dest,
  // inverse-swizzled global source (same involution as the read-side XOR).
  auto stg = [&](const bf16* base, char* ldsOp, int tidx, int slot) {
    const int tc = tidx > ntm1 ? ntm1 : tidx;   // clamped re-stage: slot never read again
#pragma unroll
    for (int r = 0; r < 2; ++r) {
      const int x  = wave * 2048 + r * 1024 + lane * 16;
      const int xs = x ^ (((x >> 6) & 3) << 4);
      gll16((const char*)base + (size_t)(xs >> 6) * 2048 + (size_t)tc * 64 + (xs & 63),
            ldsOp + slot * 16384 + wave * 2048 + r * 1024);
    }
  };

  f32x4 acc[8][4] = {};
  bf16x8 af[4], bfr[4];

  auto rdA = [&](int mh, int slot) {
#pragma unroll
    for (int i = 0; i < 4; ++i) {
      const int row = wmi * 128 + mh * 64 + i * 16 + lo;
      af[i] = *(const bf16x8*)(ldsA + slot * 16384 + ((row * 64 + hi * 16) ^ swz));
    }
  };
  auto rdB = [&](int slot) {
#pragma unroll
    for (int n = 0; n < 4; ++n) {
      const int row = wni * 64 + n * 16 + lo;
      bfr[n] = *(const bf16x8*)(ldsB + slot * 16384 + ((row * 64 + hi * 16) ^ swz));
    }
  };
  auto mmaQ = [&](int mh) {
    __builtin_amdgcn_s_setprio(1);
#pragma unroll
    for (int i = 0; i < 4; ++i)
#pragma unroll
      for (int n = 0; n < 4; ++n)
        acc[mh * 4 + i][n] = __builtin_amdgcn_mfma_f32_16x16x32_bf16(
            af[i], bfr[n], acc[mh * 4 + i][n], 0, 0, 0);
    __builtin_amdgcn_s_setprio(0);
  };

  // prologue: tile0 landed, B(1) in flight
  stg(Bp, ldsB, 0, 0);
  stg(Ap, ldsA, 0, 0);
  stg(Bp, ldsB, 1, 1);
  VMW(2);                                 // retire B(0),A(0); keep B(1)
  BARR;

#pragma unroll 2
  for (int u = 0; u < nt; ++u) {
    const int cur = u & 1;
    // ---- Phase 1: A quad0 + ALL of wave's B quarter; stage A(u+1) ----
    rdA(0, cur);
    rdB(cur);
    stg(Ap, ldsA, u + 1, cur ^ 1);
    BARR; LGKM0; SB0;
    mmaQ(0);
    BARR;
    // ---- Phase 2: A quad1, reuse bfr from registers; stage B(u+2) ----
    rdA(1, cur);
    stg(Bp, ldsB, u + 2, cur);
    BARR; LGKM0; SB0;
    mmaQ(1);
    VMW(2);                               // retire A(u+1),B(u+1); keep B(u+2)
    BARR;
  }

  // ---- epilogue ----
  if (VARIANT == 0) {
    if (!trans) {
#pragma unroll
      for (int m = 0; m < 8; ++m)
#pragma unroll
        for (int n = 0; n < 4; ++n) {
          const int c = col0 + wni * 64 + n * 16 + lo;
          const int rbase = row0 + wmi * 128 + m * 16 + hi * 4;
#pragma unroll
          for (int j = 0; j < 4; ++j)
            Cb[(size_t)(rbase + j) * 1024 + c] = (bf16)acc[m][n][j];
        }
    } else {
#pragma unroll
      for (int m = 0; m < 8; ++m)
#pragma unroll
        for (int n = 0; n < 4; ++n) {
          const int r = row0 + wmi * 128 + m * 16 + hi * 4;
          const int c = col0 + wni * 64 + n * 16 + lo;
          const int bb = r >> 10, tt = r & 1023;
          bf16x4 h = { (bf16)acc[m][n][0], (bf16)acc[m][n][1],
                       (bf16)acc[m][n][2], (bf16)acc[m][n][3] };
          *(bf16x4*)(Cb + ((size_t)bb << 20) + ((size_t)c << 10) + tt) = h;
        }
    }
  } else if (VARIANT == 2) {
    const float NINF = -__builtin_inff();
#pragma unroll
    for (int n = 0; n < 4; ++n) {
      const int s = col0 + wni * 64 + n * 16 + lo;
      const int pd = pad[(batch << 10) + s];
#pragma unroll
      for (int m = 0; m < 8; ++m) {
        const int tbase = row0 + wmi * 128 + m * 16 + hi * 4;
#pragma unroll
        for (int j = 0; j < 4; ++j) {
          float v = acc[m][n][j] * 0.03125f;          // 1/sqrt(1024)
          if (s > tbase + j + 1) v = 0.f;             // causal: raw 0, softmax skips
          else if (pd != 0) v = NINF;                 // pad: true -inf inside width
          Cb[((size_t)batch << 20) + (size_t)(tbase + j) * 1024 + s] = (bf16)v;
        }
      }
    }
  } else {
#pragma unroll
    for (int m = 0; m < 8; ++m)
#pragma unroll
      for (int n = 0; n < 4; ++n) {
        const int h2 = col0 + wni * 64 + n * 16 + lo;
        const int tbase = row0 + wmi * 128 + m * 16 + hi * 4;
#pragma unroll
        for (int j = 0; j < 4; ++j)
          Cf[((size_t)batch << 20) + (size_t)(tbase + j) * 1024 + h2] = acc[m][n][j];
      }
  }
  asm volatile("s_waitcnt vmcnt(0)" ::: "memory");   // drain clamped stages before exit
}

// ---- all three inputs fp32 -> bf16 in one launch (8192 blocks each) ----
__global__ __launch_bounds__(256) void cvt3_kernel(const float* __restrict__ s0,
                                                   const float* __restrict__ s1,
                                                   const float* __restrict__ s2,
                                                   bf16* __restrict__ d0,
                                                   bf16* __restrict__ d1,
                                                   bf16* __restrict__ d2) {
  const int seg = blockIdx.x >> 13, blk = blockIdx.x & 8191;
  const float* src = seg == 0 ? s0 : (seg == 1 ? s1 : s2);
  bf16* dst = seg == 0 ? d0 : (seg == 1 ? d1 : d2);
  const int i = (blk * 256 + threadIdx.x) * 8;
  const f32x4 a = *(const f32x4*)(src + i);
  const f32x4 b = *(const f32x4*)(src + i + 4);
  bf16x8 o = { (bf16)a[0], (bf16)a[1], (bf16)a[2], (bf16)a[3],
               (bf16)b[0], (bf16)b[1], (bf16)b[2], (bf16)b[3] };
  *(bf16x8*)(dst + i) = o;
}

// ---- all three weight matrices in one launch (512 blocks each) ----
__global__ __launch_bounds__(256) void cvtW_kernel(const float* __restrict__ s0,
                                                   const float* __restrict__ s1,
                                                   const float* __restrict__ s2,
                                                   bf16* __restrict__ d0,
                                                   bf16* __restrict__ d1,
                                                   bf16* __restrict__ d2) {
  const int seg = blockIdx.x >> 9, blk = blockIdx.x & 511;
  const float* src = seg == 0 ? s0 : (seg == 1 ? s1 : s2);
  bf16* dst = seg == 0 ? d0 : (seg == 1 ? d1 : d2);
  const int i = (blk * 256 + threadIdx.x) * 8;
  const f32x4 a = *(const f32x4*)(src + i);
  const f32x4 b = *(const f32x4*)(src + i + 4);
  bf16x8 o = { (bf16)a[0], (bf16)a[1], (bf16)a[2], (bf16)a[3],
               (bf16)b[0], (bf16)b[1], (bf16)b[2], (bf16)b[3] };
  *(bf16x8*)(dst + i) = o;
}

// ---- the single valid element on each jt==it+1 tile: S[t=it*256+255][s=(it+1)*256] ----
__global__ __launch_bounds__(64) void corner_kernel(const bf16* __restrict__ Q,
                                                    const bf16* __restrict__ K,
                                                    const int* __restrict__ pad,
                                                    bf16* __restrict__ S) {
  const int b = blockIdx.x / 3, it = blockIdx.x % 3;
  const int t = it * 256 + 255, s = (it + 1) * 256;
  const int lane = threadIdx.x;
  const bf16* q = Q + ((size_t)b << 20) + (size_t)t * 1024 + lane * 16;
  const bf16* k = K + ((size_t)b << 20) + (size_t)s * 1024 + lane * 16;
  bf16x8 q0 = *(const bf16x8*)q, q1 = *(const bf16x8*)(q + 8);
  bf16x8 k0 = *(const bf16x8*)k, k1 = *(const bf16x8*)(k + 8);
  float d = 0.f;
#pragma unroll
  for (int j = 0; j < 8; ++j) d += (float)q0[j] * (float)k0[j] + (float)q1[j] * (float)k1[j];
#pragma unroll
  for (int o = 32; o; o >>= 1) d += __shfl_xor(d, o, 64);
  if (lane == 0) {
    float v = d * 0.03125f;
    if (pad[(b << 10) + s] != 0) v = -__builtin_inff();
    S[((size_t)b << 20) + (size_t)t * 1024 + s] = (bf16)v;
  }
}

// ---- row softmax in place over valid prefix w = t+2 (causal tail stays 0) ----
__global__ __launch_bounds__(256) void softmax_kernel(bf16* __restrict__ S) {
  const int row  = blockIdx.x * 4 + (threadIdx.x >> 6);
  const int lane = threadIdx.x & 63;
  const int t = row & 1023;
  const int w = min(1024, t + 2);
  const bool act = lane * 16 < w;
  bf16* r = S + (size_t)row * 1024 + lane * 16;
  bf16x8 v0 = {}, v1 = {};
  float f[16];
#pragma unroll
  for (int j = 0; j < 16; ++j) f[j] = -1e30f;
  if (act) {
    v0 = *(const bf16x8*)r;
    v1 = *(const bf16x8*)(r + 8);
#pragma unroll
    for (int j = 0; j < 16; ++j)
      if (lane * 16 + j < w) f[j] = (float)(j < 8 ? v0[j] : v1[j - 8]);
  }
  float m = f[0];
#pragma unroll
  for (int j = 1; j < 16; ++j) m = fmaxf(m, f[j]);
#pragma unroll
  for (int o = 32; o; o >>= 1) m = fmaxf(m, __shfl_xor(m, o, 64));
  float sum = 0.f;
  float e[16];
#pragma unroll
  for (int j = 0; j < 16; ++j) { e[j] = __expf(f[j] - m); sum += e[j]; }
#pragma unroll
  for (int o = 32; o; o >>= 1) sum += __shfl_xor(sum, o, 64);
  const float inv = 1.0f / sum;
  if (act) {
#pragma unroll
    for (int j = 0; j < 8; ++j) {
      v0[j] = (bf16)(lane * 16 + j < w ? e[j] * inv : 0.f);
      v1[j] = (bf16)(lane * 16 + 8 + j < w ? e[8 + j] * inv : 0.f);
    }
    *(bf16x8*)r = v0;
    *(bf16x8*)(r + 8) = v1;
  }
}

extern "C" void kernel_launch(void* const* d_in, const int* in_sizes, int n_in,
                              void* d_out, int out_size, void* d_ws, size_t ws_size,
                              hipStream_t stream) {
  const float* key   = (const float*)d_in[0];
  const float* query = (const float*)d_in[1];
  const float* value = (const float*)d_in[2];
  const int*   pad   = (const int*)d_in[3];
  const float* Wk    = (const float*)d_in[4];
  const float* Wq    = (const float*)d_in[5];
  const float* Wv    = (const float*)d_in[6];
  float* out = (float*)d_out;

  // ws (bf16 elems): Wk,Wq,Wv (1M each) | q 16M | k 16M | vT 16M | S 16M
  // Scratch for bf16 inputs: Xq = S (not live until qk); Xk,Xv = d_out
  // (pv fully rewrites d_out at the end).
  bf16* Wkb = (bf16*)d_ws;
  bf16* Wqb = Wkb + (1 << 20);
  bf16* Wvb = Wqb + (1 << 20);
  bf16* qb  = Wvb + (1 << 20);
  bf16* kb  = qb  + (16 << 20);
  bf16* vT  = kb  + (16 << 20);
  bf16* S   = vT  + (16 << 20);
  bf16* Xq  = S;
  bf16* Xk  = (bf16*)d_out;
  bf16* Xv  = Xk + (16 << 20);

  hipFuncSetAttribute(reinterpret_cast<const void*>(&gemm8<0>),
                      hipFuncAttributeMaxDynamicSharedMemorySize, 65536);
  hipFuncSetAttribute(reinterpret_cast<const void*>(&gemm8<2>),
                      hipFuncAttributeMaxDynamicSharedMemorySize, 65536);
  hipFuncSetAttribute(reinterpret_cast<const void*>(&gemm8<3>),
                      hipFuncAttributeMaxDynamicSharedMemorySize, 65536);

  cvtW_kernel<<<1536, 256, 0, stream>>>(Wk, Wq, Wv, Wkb, Wqb, Wvb);
  cvt3_kernel<<<24576, 256, 0, stream>>>(query, key, value, Xq, Xk, Xv);

  // merged projections: q = Xq*Wq^T, k = Xk*Wk^T, vT = (Xv*Wv^T)^T
  gemm8<0><<<768, 512, 65536, stream>>>(Xq, Xk, Xv, Wqb, Wkb, Wvb,
                                        qb, kb, vT, nullptr, nullptr);

  gemm8<2><<<256, 512, 65536, stream>>>(qb, nullptr, nullptr, kb, nullptr, nullptr,
                                        S, nullptr, nullptr, nullptr, pad);
  corner_kernel<<<48, 64, 0, stream>>>(qb, kb, pad, S);
  softmax_kernel<<<4096, 256, 0, stream>>>(S);
  gemm8<3><<<256, 512, 65536, stream>>>(S, nullptr, nullptr, vT, nullptr, nullptr,
                                        nullptr, nullptr, nullptr, out, nullptr);
}

// Round 9
// 238.133 us; speedup vs baseline: 1.4192x; 1.0493x over previous
//
#include <hip/hip_runtime.h>
#include <hip/hip_bf16.h>
#include <stdint.h>

typedef __bf16 bf16;
typedef __attribute__((ext_vector_type(8))) __bf16 bf16x8;
typedef __attribute__((ext_vector_type(4))) __bf16 bf16x4;
typedef __attribute__((ext_vector_type(4))) float  f32x4;

// ---- async global->LDS, 16B per lane, dest = wave-uniform base (+ lane*16 in HW) ----
static __device__ __forceinline__ void gll16(const void* g, void* lds_base) {
  __builtin_amdgcn_global_load_lds((__attribute__((address_space(1))) void*)g,
                                   (__attribute__((address_space(3))) void*)lds_base,
                                   16, 0, 0);
}

#define BARR  __builtin_amdgcn_s_barrier()
#define VMW(N) asm volatile("s_waitcnt vmcnt(" #N ")" ::: "memory")
#define LGKM0 asm volatile("s_waitcnt lgkmcnt(0)" ::: "memory")
#define SB0   __builtin_amdgcn_sched_barrier(0)

// ============================================================================
// 256x256 BT-GEMM (D = A*B^T, both K-contiguous, ld=1024), BK=32, 8 waves
// (2Mx4N), 2 phases per K-tile (B quarter in regs), double-buffered 64 KiB
// LDS -> 2 blocks/CU. Swizzle FIXED vs R8: key = ((row>>1)&3)<<4 (addr bits
// 8:7 -> 4:5, true involution; uniform 8-lanes/16B-granule => conflict-free;
// R8's (row&3) key was 4-way-conflicted, 9.4e6/dispatch).
// Counted vmcnt(2)/K-tile; prologue {B(0),A(0),B(1); vmcnt(2)}.
// VARIANT 0: grid 512 => seg=id>>8: seg0 D=BT(a0,b0)->c0 row-major,
//            seg1 D=BT(a1,b1)->c1 per-batch transposed [b][n][t].
//            grid 16 (P-GEMM) => seg0 only, M=N=1024.
// VARIANT 2: qk  S=BT(Y,Xk) per batch (scale 1/32; causal writes 0, pad -inf;
//            jt==it+1 zero-fill, jt>it+1 skipped).
// VARIANT 3: pv  out=BT(S,vT) f32, K causally truncated.
// ============================================================================
template <int VARIANT>
__global__ __launch_bounds__(512, 2) void gemm8(const bf16* __restrict__ a0,
                                                const bf16* __restrict__ a1,
                                                const bf16* __restrict__ b0,
                                                const bf16* __restrict__ b1,
                                                bf16* __restrict__ c0,
                                                bf16* __restrict__ c1,
                                                float* __restrict__ Cf,
                                                const int* __restrict__ pad) {
  extern __shared__ char smem[];         // A: 2 x 16KB | B: 2 x 16KB
  char* ldsA = smem;
  char* ldsB = smem + 32768;

  const int tid = threadIdx.x;
  const int lane = tid & 63, wave = tid >> 6;
  const int lo = lane & 15, hi = lane >> 4;
  const int wmi = wave >> 2, wni = wave & 3;
  const int swz = ((lo >> 1) & 3) << 4;  // read-side XOR key = ((row>>1)&3)<<4

  // XCD-chunked bijective swizzle (gridDim.x % 8 == 0 for all launches)
  const int nwg = gridDim.x;
  const int id = (blockIdx.x % 8) * (nwg >> 3) + blockIdx.x / 8;

  int row0, col0, nt, batch = 0, trans = 0;
  const bf16 *Ap, *Bp;
  bf16* Cb;
  if (VARIANT == 0) {
    const int seg = id >> 8, idl = id & 255;
    row0 = (idl >> 2) * 256; col0 = (idl & 3) * 256; nt = 32;
    trans = seg;
    const bf16* As = seg ? a1 : a0;
    const bf16* Bs = seg ? b1 : b0;
    Cb = seg ? c1 : c0;
    Ap = As + (size_t)row0 * 1024;
    Bp = Bs + (size_t)col0 * 1024;
  } else {
    batch = id >> 4;
    const int r = id & 15, it = r >> 2, jt = r & 3;
    row0 = it * 256; col0 = jt * 256;
    nt = (VARIANT == 3) ? min(32, 8 * it + 10) : 32;   // pv causal truncation (even)
    if (VARIANT == 2 && jt > it + 1) return;           // never read downstream
    if (VARIANT == 2 && jt == it + 1) {                // zero-fill (corner fixed later)
      bf16* Sb = c0 + ((size_t)batch << 20);
      bf16x8 z = {};
#pragma unroll
      for (int q = 0; q < 16; ++q) {
        const int off = (q * 512 + tid) * 8;
        *(bf16x8*)(Sb + (size_t)(row0 + (off >> 8)) * 1024 + col0 + (off & 255)) = z;
      }
      return;
    }
    Ap = a0 + ((size_t)batch << 20) + (size_t)row0 * 1024;
    Bp = b0 + ((size_t)batch << 20) + (size_t)col0 * 1024;
    Cb = c0;
  }
  const int ntm1 = nt - 1;

  // stage one full 256x32 operand K-tile (16KB): 2 gll/wave, linear LDS dest,
  // inverse-swizzled global source (same involution as the read-side XOR;
  // key only permutes the 16B slot within each 64B row: bits 4:5 ^= bits 8:7).
  auto stg = [&](const bf16* base, char* ldsOp, int tidx, int slot) {
    const int tc = tidx > ntm1 ? ntm1 : tidx;   // clamped re-stage: slot never read again
#pragma unroll
    for (int r = 0; r < 2; ++r) {
      const int x  = wave * 2048 + r * 1024 + lane * 16;
      const int xs = x ^ (((x >> 7) & 3) << 4);
      gll16((const char*)base + (size_t)(xs >> 6) * 2048 + (size_t)tc * 64 + (xs & 63),
            ldsOp + slot * 16384 + wave * 2048 + r * 1024);
    }
  };

  f32x4 acc[8][4] = {};
  bf16x8 af[4], bfr[4];

  auto rdA = [&](int mh, int slot) {
#pragma unroll
    for (int i = 0; i < 4; ++i) {
      const int row = wmi * 128 + mh * 64 + i * 16 + lo;
      af[i] = *(const bf16x8*)(ldsA + slot * 16384 + ((row * 64 + hi * 16) ^ swz));
    }
  };
  auto rdB = [&](int slot) {
#pragma unroll
    for (int n = 0; n < 4; ++n) {
      const int row = wni * 64 + n * 16 + lo;
      bfr[n] = *(const bf16x8*)(ldsB + slot * 16384 + ((row * 64 + hi * 16) ^ swz));
    }
  };
  auto mmaQ = [&](int mh) {
    __builtin_amdgcn_s_setprio(1);
#pragma unroll
    for (int i = 0; i < 4; ++i)
#pragma unroll
      for (int n = 0; n < 4; ++n)
        acc[mh * 4 + i][n] = __builtin_amdgcn_mfma_f32_16x16x32_bf16(
            af[i], bfr[n], acc[mh * 4 + i][n], 0, 0, 0);
    __builtin_amdgcn_s_setprio(0);
  };

  // prologue: tile0 landed, B(1) in flight
  stg(Bp, ldsB, 0, 0);
  stg(Ap, ldsA, 0, 0);
  stg(Bp, ldsB, 1, 1);
  VMW(2);                                 // retire B(0),A(0); keep B(1)
  BARR;

#pragma unroll 2
  for (int u = 0; u < nt; ++u) {
    const int cur = u & 1;
    // ---- Phase 1: A quad0 + ALL of wave's B quarter; stage A(u+1) ----
    rdA(0, cur);
    rdB(cur);
    stg(Ap, ldsA, u + 1, cur ^ 1);
    BARR; LGKM0; SB0;
    mmaQ(0);
    BARR;
    // ---- Phase 2: A quad1, reuse bfr from registers; stage B(u+2) ----
    rdA(1, cur);
    stg(Bp, ldsB, u + 2, cur);
    BARR; LGKM0; SB0;
    mmaQ(1);
    VMW(2);                               // retire A(u+1),B(u+1); keep B(u+2)
    BARR;
  }

  // ---- epilogue ----
  if (VARIANT == 0) {
    if (!trans) {
#pragma unroll
      for (int m = 0; m < 8; ++m)
#pragma unroll
        for (int n = 0; n < 4; ++n) {
          const int c = col0 + wni * 64 + n * 16 + lo;
          const int rbase = row0 + wmi * 128 + m * 16 + hi * 4;
#pragma unroll
          for (int j = 0; j < 4; ++j)
            Cb[(size_t)(rbase + j) * 1024 + c] = (bf16)acc[m][n][j];
        }
    } else {
#pragma unroll
      for (int m = 0; m < 8; ++m)
#pragma unroll
        for (int n = 0; n < 4; ++n) {
          const int r = row0 + wmi * 128 + m * 16 + hi * 4;
          const int c = col0 + wni * 64 + n * 16 + lo;
          const int bb = r >> 10, tt = r & 1023;
          bf16x4 h = { (bf16)acc[m][n][0], (bf16)acc[m][n][1],
                       (bf16)acc[m][n][2], (bf16)acc[m][n][3] };
          *(bf16x4*)(Cb + ((size_t)bb << 20) + ((size_t)c << 10) + tt) = h;
        }
    }
  } else if (VARIANT == 2) {
    const float NINF = -__builtin_inff();
#pragma unroll
    for (int n = 0; n < 4; ++n) {
      const int s = col0 + wni * 64 + n * 16 + lo;
      const int pd = pad[(batch << 10) + s];
#pragma unroll
      for (int m = 0; m < 8; ++m) {
        const int tbase = row0 + wmi * 128 + m * 16 + hi * 4;
#pragma unroll
        for (int j = 0; j < 4; ++j) {
          float v = acc[m][n][j] * 0.03125f;          // 1/sqrt(1024)
          if (s > tbase + j + 1) v = 0.f;             // causal: raw 0, softmax skips
          else if (pd != 0) v = NINF;                 // pad: true -inf inside width
          Cb[((size_t)batch << 20) + (size_t)(tbase + j) * 1024 + s] = (bf16)v;
        }
      }
    }
  } else {
#pragma unroll
    for (int m = 0; m < 8; ++m)
#pragma unroll
      for (int n = 0; n < 4; ++n) {
        const int h2 = col0 + wni * 64 + n * 16 + lo;
        const int tbase = row0 + wmi * 128 + m * 16 + hi * 4;
#pragma unroll
        for (int j = 0; j < 4; ++j)
          Cf[((size_t)batch << 20) + (size_t)(tbase + j) * 1024 + h2] = acc[m][n][j];
      }
  }
  asm volatile("s_waitcnt vmcnt(0)" ::: "memory");   // drain clamped stages before exit
}

// ---- all three inputs fp32 -> bf16 in one launch (8192 blocks each) ----
__global__ __launch_bounds__(256) void cvt3_kernel(const float* __restrict__ s0,
                                                   const float* __restrict__ s1,
                                                   const float* __restrict__ s2,
                                                   bf16* __restrict__ d0,
                                                   bf16* __restrict__ d1,
                                                   bf16* __restrict__ d2) {
  const int seg = blockIdx.x >> 13, blk = blockIdx.x & 8191;
  const float* src = seg == 0 ? s0 : (seg == 1 ? s1 : s2);
  bf16* dst = seg == 0 ? d0 : (seg == 1 ? d1 : d2);
  const int i = (blk * 256 + threadIdx.x) * 8;
  const f32x4 a = *(const f32x4*)(src + i);
  const f32x4 b = *(const f32x4*)(src + i + 4);
  bf16x8 o = { (bf16)a[0], (bf16)a[1], (bf16)a[2], (bf16)a[3],
               (bf16)b[0], (bf16)b[1], (bf16)b[2], (bf16)b[3] };
  *(bf16x8*)(dst + i) = o;
}

// ---- weights: Wq,Wk -> TRANSPOSED bf16 (for the P-GEMM); Wv -> straight ----
// blocks [0,256) Wq-T, [256,512) Wk-T (64x64 LDS tiles), [512,1024) Wv straight
__global__ __launch_bounds__(256) void cvtWT_kernel(const float* __restrict__ Wq,
                                                    const float* __restrict__ Wk,
                                                    const float* __restrict__ Wv,
                                                    bf16* __restrict__ WqT,
                                                    bf16* __restrict__ WkT,
                                                    bf16* __restrict__ Wvb) {
  const int t = threadIdx.x;
  if (blockIdx.x >= 512) {
    const int i = ((blockIdx.x - 512) * 256 + t) * 8;
    const f32x4 a = *(const f32x4*)(Wv + i);
    const f32x4 b = *(const f32x4*)(Wv + i + 4);
    bf16x8 o = { (bf16)a[0], (bf16)a[1], (bf16)a[2], (bf16)a[3],
                 (bf16)b[0], (bf16)b[1], (bf16)b[2], (bf16)b[3] };
    *(bf16x8*)(Wvb + i) = o;
    return;
  }
  const int m = blockIdx.x >> 8;
  const float* src = m ? Wk : Wq;
  bf16* dst = m ? WkT : WqT;
  const int tile = blockIdx.x & 255;
  const int tr = (tile >> 4) * 64, tc = (tile & 15) * 64;
  __shared__ bf16 s[64][72];              // 144B row stride: 16B-aligned
#pragma unroll
  for (int it = 0; it < 4; ++it) {
    const int row = it * 16 + (t >> 4), col = (t & 15) * 4;
    const f32x4 v = *(const f32x4*)(src + (size_t)(tr + row) * 1024 + tc + col);
#pragma unroll
    for (int j = 0; j < 4; ++j) s[col + j][row] = (bf16)v[j];
  }
  __syncthreads();
  const int c = t >> 2, rb = (t & 3) * 16;
  bf16* d = dst + (size_t)(tc + c) * 1024 + tr + rb;
  *(bf16x8*)(d)     = *(const bf16x8*)&s[c][rb];
  *(bf16x8*)(d + 8) = *(const bf16x8*)&s[c][rb + 8];
}

// ---- the single valid element on each jt==it+1 tile: S[t=it*256+255][s=(it+1)*256] ----
__global__ __launch_bounds__(64) void corner_kernel(const bf16* __restrict__ Y,
                                                    const bf16* __restrict__ Xk,
                                                    const int* __restrict__ pad,
                                                    bf16* __restrict__ S) {
  const int b = blockIdx.x / 3, it = blockIdx.x % 3;
  const int t = it * 256 + 255, s = (it + 1) * 256;
  const int lane = threadIdx.x;
  const bf16* y = Y  + ((size_t)b << 20) + (size_t)t * 1024 + lane * 16;
  const bf16* k = Xk + ((size_t)b << 20) + (size_t)s * 1024 + lane * 16;
  bf16x8 q0 = *(const bf16x8*)y, q1 = *(const bf16x8*)(y + 8);
  bf16x8 k0 = *(const bf16x8*)k, k1 = *(const bf16x8*)(k + 8);
  float d = 0.f;
#pragma unroll
  for (int j = 0; j < 8; ++j) d += (float)q0[j] * (float)k0[j] + (float)q1[j] * (float)k1[j];
#pragma unroll
  for (int o = 32; o; o >>= 1) d += __shfl_xor(d, o, 64);
  if (lane == 0) {
    float v = d * 0.03125f;
    if (pad[(b << 10) + s] != 0) v = -__builtin_inff();
    S[((size_t)b << 20) + (size_t)t * 1024 + s] = (bf16)v;
  }
}

// ---- row softmax in place over valid prefix w = t+2 (causal tail stays 0) ----
__global__ __launch_bounds__(256) void softmax_kernel(bf16* __restrict__ S) {
  const int row  = blockIdx.x * 4 + (threadIdx.x >> 6);
  const int lane = threadIdx.x & 63;
  const int t = row & 1023;
  const int w = min(1024, t + 2);
  const bool act = lane * 16 < w;
  bf16* r = S + (size_t)row * 1024 + lane * 16;
  bf16x8 v0 = {}, v1 = {};
  float f[16];
#pragma unroll
  for (int j = 0; j < 16; ++j) f[j] = -1e30f;
  if (act) {
    v0 = *(const bf16x8*)r;
    v1 = *(const bf16x8*)(r + 8);
#pragma unroll
    for (int j = 0; j < 16; ++j)
      if (lane * 16 + j < w) f[j] = (float)(j < 8 ? v0[j] : v1[j - 8]);
  }
  float m = f[0];
#pragma unroll
  for (int j = 1; j < 16; ++j) m = fmaxf(m, f[j]);
#pragma unroll
  for (int o = 32; o; o >>= 1) m = fmaxf(m, __shfl_xor(m, o, 64));
  float sum = 0.f;
  float e[16];
#pragma unroll
  for (int j = 0; j < 16; ++j) { e[j] = __expf(f[j] - m); sum += e[j]; }
#pragma unroll
  for (int o = 32; o; o >>= 1) sum += __shfl_xor(sum, o, 64);
  const float inv = 1.0f / sum;
  if (act) {
#pragma unroll
    for (int j = 0; j < 8; ++j) {
      v0[j] = (bf16)(lane * 16 + j < w ? e[j] * inv : 0.f);
      v1[j] = (bf16)(lane * 16 + 8 + j < w ? e[8 + j] * inv : 0.f);
    }
    *(bf16x8*)r = v0;
    *(bf16x8*)(r + 8) = v1;
  }
}

extern "C" void kernel_launch(void* const* d_in, const int* in_sizes, int n_in,
                              void* d_out, int out_size, void* d_ws, size_t ws_size,
                              hipStream_t stream) {
  const float* key   = (const float*)d_in[0];
  const float* query = (const float*)d_in[1];
  const float* value = (const float*)d_in[2];
  const int*   pad   = (const int*)d_in[3];
  const float* Wk    = (const float*)d_in[4];
  const float* Wq    = (const float*)d_in[5];
  const float* Wv    = (const float*)d_in[6];
  float* out = (float*)d_out;

  // ws (bf16 elems): WqT,WkT,Wvb,P (1M each) | Y 16M | vT 16M | S 16M
  // Scratch: Xq = S slot (not live until qk writes S); Xk,Xv = d_out
  // (pv fully rewrites d_out at the end).
  bf16* WqT = (bf16*)d_ws;
  bf16* WkT = WqT + (1 << 20);
  bf16* Wvb = WkT + (1 << 20);
  bf16* P   = Wvb + (1 << 20);
  bf16* Y   = P   + (1 << 20);
  bf16* vT  = Y   + (16 << 20);
  bf16* S   = vT  + (16 << 20);
  bf16* Xq  = S;
  bf16* Xk  = (bf16*)d_out;
  bf16* Xv  = Xk + (16 << 20);

  hipFuncSetAttribute(reinterpret_cast<const void*>(&gemm8<0>),
                      hipFuncAttributeMaxDynamicSharedMemorySize, 65536);
  hipFuncSetAttribute(reinterpret_cast<const void*>(&gemm8<2>),
                      hipFuncAttributeMaxDynamicSharedMemorySize, 65536);
  hipFuncSetAttribute(reinterpret_cast<const void*>(&gemm8<3>),
                      hipFuncAttributeMaxDynamicSharedMemorySize, 65536);

  cvtWT_kernel<<<1024, 256, 0, stream>>>(Wq, Wk, Wv, WqT, WkT, Wvb);
  // P[f,e] = sum_h Wk[h,f]*Wq[h,e] = BT(WkT, WqT)
  gemm8<0><<<16, 512, 65536, stream>>>(WkT, nullptr, WqT, nullptr,
                                       P, nullptr, nullptr, nullptr);
  cvt3_kernel<<<24576, 256, 0, stream>>>(query, key, value, Xq, Xk, Xv);

  // merged: seg0 Y = BT(Xq, P); seg1 vT = BT(Xv, Wvb) transposed epilogue
  gemm8<0><<<512, 512, 65536, stream>>>(Xq, Xv, P, Wvb, Y, vT, nullptr, nullptr);

  // S = BT(Y, Xk) per batch  (algebraically == q k^T)
  gemm8<2><<<256, 512, 65536, stream>>>(Y, nullptr, Xk, nullptr,
                                        S, nullptr, nullptr, pad);
  corner_kernel<<<48, 64, 0, stream>>>(Y, Xk, pad, S);
  softmax_kernel<<<4096, 256, 0, stream>>>(S);
  gemm8<3><<<256, 512, 65536, stream>>>(S, nullptr, vT, nullptr,
                                        nullptr, nullptr, out, nullptr);
}